// Round 1
// baseline (2611.454 us; speedup 1.0000x reference)
//
#include <hip/hip_runtime.h>

using bf16 = __bf16;
typedef bf16 bf16x8 __attribute__((ext_vector_type(8)));
typedef float f32x4 __attribute__((ext_vector_type(4)));

#define MFMA16(a, b, c) __builtin_amdgcn_mfma_f32_16x16x32_bf16(a, b, c, 0, 0, 0)

// ---------------- helpers ----------------

__device__ __forceinline__ bf16x8 to_bf16x8(float4 a, float4 b) {
    bf16x8 v;
    v[0] = (bf16)a.x; v[1] = (bf16)a.y; v[2] = (bf16)a.z; v[3] = (bf16)a.w;
    v[4] = (bf16)b.x; v[5] = (bf16)b.y; v[6] = (bf16)b.z; v[7] = (bf16)b.w;
    return v;
}

// A-fragment from a swizzled row-major LDS tile [rows][ldK] bf16.
// Swizzle: byte_off_in_row ^= ((row&7)<<4). Requires ldK*2 % 128 == 0.
__device__ __forceinline__ bf16x8 lds_afrag(const char* smem, int ldK, int mbase, int kbase, int lane) {
    int r = mbase + (lane & 15);
    int off = (kbase + ((lane >> 4) << 3)) << 1;
    off ^= (r & 7) << 4;
    return *(const bf16x8*)(smem + r * (ldK << 1) + off);
}

// B-fragment from global WT[N][K] bf16 (i.e., W transposed): 8 contiguous k at row n.
__device__ __forceinline__ bf16x8 glb_bfrag(const bf16* __restrict__ WT, int K, int nbase, int kbase, int lane) {
    int n = nbase + (lane & 15);
    int k = kbase + ((lane >> 4) << 3);
    return *(const bf16x8*)(WT + (size_t)n * K + k);
}

// ---------------- small kernels ----------------

// WT[n*ldT + k0 + k] = bf16(W[k*N + n])
__global__ void k_transpose(const float* __restrict__ W, bf16* __restrict__ WT,
                            int K, int N, int ldT, int k0) {
    int idx = blockIdx.x * 256 + threadIdx.x;
    if (idx < K * N) {
        int k = idx / N, n = idx - k * N;
        WT[(size_t)n * ldT + k0 + k] = (bf16)W[idx];
    }
}

__global__ void k_deg(const int* __restrict__ dst, float* __restrict__ deg, int E) {
    int e = blockIdx.x * 256 + threadIdx.x;
    if (e < E) atomicAdd(&deg[dst[e]], 1.0f);
}

// single-block exclusive scan of deg -> offsets; also invdeg = 1/max(deg,1)
__global__ void k_scan(const float* __restrict__ deg, unsigned* __restrict__ offsets,
                       float* __restrict__ invdeg, int N) {
    __shared__ unsigned wsum[16];
    __shared__ unsigned carry_s, tot_s;
    const int tid = threadIdx.x, lane = tid & 63, wid = tid >> 6;
    if (tid == 0) carry_s = 0;
    __syncthreads();
    for (int base = 0; base < N; base += 1024) {
        int i = base + tid;
        unsigned v = (i < N) ? (unsigned)deg[i] : 0u;
        unsigned inc = v;
        #pragma unroll
        for (int d = 1; d < 64; d <<= 1) {
            unsigned t = (unsigned)__shfl_up((int)inc, d, 64);
            if (lane >= d) inc += t;
        }
        if (lane == 63) wsum[wid] = inc;
        __syncthreads();
        if (wid == 0) {
            unsigned wv = (lane < 16) ? wsum[lane] : 0u;
            unsigned winc = wv;
            #pragma unroll
            for (int d = 1; d < 16; d <<= 1) {
                unsigned t = (unsigned)__shfl_up((int)winc, d, 16);
                if ((lane & 15) >= d) winc += t;
            }
            if (lane < 16) wsum[lane] = winc - wv;
            if (lane == 15) tot_s = winc;
        }
        __syncthreads();
        if (i < N) {
            offsets[i] = carry_s + wsum[wid] + (inc - v);
            invdeg[i] = 1.0f / fmaxf(deg[i], 1.0f);
        }
        __syncthreads();
        if (tid == 0) carry_s += tot_s;
        __syncthreads();
    }
    if (tid == 0) offsets[N] = carry_s;
}

__global__ void k_scatter(const int* __restrict__ dst, const unsigned* __restrict__ offsets,
                          unsigned* __restrict__ cursor, unsigned* __restrict__ eid, int E) {
    int e = blockIdx.x * 256 + threadIdx.x;
    if (e < E) {
        int d = dst[e];
        unsigned p = atomicAdd(&cursor[d], 1u);
        eid[offsets[d] + p] = (unsigned)e;
    }
}

// per-node mean of concat(x[src], ef) over incoming edges -> sm [N][192] f32
__global__ __launch_bounds__(256)
void k_agg(const float* __restrict__ xin, const float* __restrict__ ef, const int* __restrict__ src,
           const unsigned* __restrict__ offsets, const float* __restrict__ invdeg,
           const unsigned* __restrict__ eid, float* __restrict__ sm, int N) {
    const int lane = threadIdx.x & 63, w = threadIdx.x >> 6;
    int nb = blockIdx.x * 16 + w * 4;
    for (int j = 0; j < 4; ++j) {
        int n = nb + j;
        if (n >= N) return;
        unsigned o0 = offsets[n], o1 = offsets[n + 1];
        float s0 = 0.f, s1 = 0.f, s2 = 0.f;
        for (unsigned t = o0; t < o1; ++t) {
            int e = (int)eid[t];
            int v = src[e];
            s0 += xin[(size_t)v * 128 + lane];
            s1 += xin[(size_t)v * 128 + 64 + lane];
            s2 += ef[(size_t)e * 64 + lane];
        }
        float g = invdeg[n];
        sm[(size_t)n * 192 + lane] = s0 * g;
        sm[(size_t)n * 192 + 64 + lane] = s1 * g;
        sm[(size_t)n * 192 + 128 + lane] = s2 * g;
    }
}

// x_out = relu(concat(x, sm) @ Wcat + b_self + (deg>0 ? b_nb : 0)); Wcat = [W_self; W_nb] [320][128]
__global__ __launch_bounds__(256)
void k_nodegemm(const float* __restrict__ xin, const float* __restrict__ sm,
                const bf16* __restrict__ WcatT,
                const float* __restrict__ b_self, const float* __restrict__ b_nb,
                const unsigned* __restrict__ offsets,
                float* __restrict__ xout, int N) {
    __shared__ char smem[64 * 320 * 2];
    const int tid = threadIdx.x, lane = tid & 63, w = tid >> 6;
    const int n0 = blockIdx.x * 64;
    for (int it = tid; it < 64 * 40; it += 256) {
        int r = it / 40, c = it - r * 40;
        int node = n0 + r;
        float4 fa = {0, 0, 0, 0}, fb = {0, 0, 0, 0};
        if (node < N) {
            int base = c * 8;
            const float* p = (base < 128) ? xin + (size_t)node * 128 + base
                                          : sm + (size_t)node * 192 + (base - 128);
            fa = *(const float4*)p;
            fb = *(const float4*)(p + 4);
        }
        bf16x8 v = to_bf16x8(fa, fb);
        *(bf16x8*)(smem + r * 640 + ((c * 16) ^ ((r & 7) << 4))) = v;
    }
    __syncthreads();

    f32x4 acc[4][2];
    #pragma unroll
    for (int m = 0; m < 4; ++m)
        #pragma unroll
        for (int n = 0; n < 2; ++n) acc[m][n] = (f32x4){0.f, 0.f, 0.f, 0.f};

    for (int ks = 0; ks < 10; ++ks) {
        bf16x8 a[4];
        #pragma unroll
        for (int m = 0; m < 4; ++m) a[m] = lds_afrag(smem, 320, m * 16, ks * 32, lane);
        #pragma unroll
        for (int n = 0; n < 2; ++n) {
            bf16x8 b = glb_bfrag(WcatT, 320, w * 32 + n * 16, ks * 32, lane);
            #pragma unroll
            for (int m = 0; m < 4; ++m) acc[m][n] = MFMA16(a[m], b, acc[m][n]);
        }
    }

    #pragma unroll
    for (int n = 0; n < 2; ++n) {
        int col = w * 32 + n * 16 + (lane & 15);
        float bs = b_self[col], bn = b_nb[col];
        #pragma unroll
        for (int m = 0; m < 4; ++m)
            #pragma unroll
            for (int rr = 0; rr < 4; ++rr) {
                int row = m * 16 + ((lane >> 4) << 2) + rr;
                int node = n0 + row;
                if (node < N) {
                    bool hd = offsets[node + 1] > offsets[node];
                    xout[(size_t)node * 128 + col] =
                        fmaxf(acc[m][n][rr] + bs + (hd ? bn : 0.f), 0.f);
                }
            }
    }
}

__global__ void k_finalize(const float* __restrict__ sum, const float* __restrict__ sq,
                           const float* __restrict__ g, const float* __restrict__ beta,
                           float* __restrict__ scale, float* __restrict__ shift,
                           int n, float invE) {
    int i = blockIdx.x * 256 + threadIdx.x;
    if (i < n) {
        float m = sum[i] * invE;
        float v = sq[i] * invE - m * m;
        float sc = g[i] * rsqrtf(v + 1e-5f);
        scale[i] = sc;
        shift[i] = beta[i] - m * sc;
    }
}

// ---------------- fused edge MLP (3 passes) ----------------
// PASS 0: h1 stats. PASS 1: h1->bn->a1->h2 stats. PASS 2: full chain -> out.
template <int PASS>
__global__ __launch_bounds__(256, 2)
void k_mlp(const float* __restrict__ x, const int* __restrict__ ei, const float* __restrict__ ef,
           const bf16* __restrict__ W1T, const float* __restrict__ b1,
           const bf16* __restrict__ W2T, const float* __restrict__ b2,
           const bf16* __restrict__ W3T, const float* __restrict__ b3,
           const bf16* __restrict__ W4T, const float* __restrict__ b4,
           const bf16* __restrict__ W5T, const float* __restrict__ b5,
           const float* __restrict__ W6, const float* __restrict__ b6,
           const float* __restrict__ scale1, const float* __restrict__ shift1,
           const float* __restrict__ scale2, const float* __restrict__ shift2,
           float* __restrict__ sum1, float* __restrict__ sq1,
           float* __restrict__ sum2, float* __restrict__ sq2,
           float* __restrict__ out, int E) {
    __shared__ char smem[65536];
    const int tid = threadIdx.x, lane = tid & 63, w = tid >> 6;
    const int e0 = blockIdx.x * 64;
    const int* src = ei;
    const int* dst = ei + E;

    // pair tile [64][320] bf16, swizzled
    for (int it = tid; it < 64 * 40; it += 256) {
        int r = it / 40, c = it - r * 40;
        int ge = e0 + r;
        float4 fa = {0, 0, 0, 0}, fb = {0, 0, 0, 0};
        if (ge < E) {
            int base = c * 8;
            const float* p;
            if (base < 128)      p = x + (size_t)src[ge] * 128 + base;
            else if (base < 256) p = x + (size_t)dst[ge] * 128 + (base - 128);
            else                 p = ef + (size_t)ge * 64 + (base - 256);
            fa = *(const float4*)p;
            fb = *(const float4*)(p + 4);
        }
        bf16x8 v = to_bf16x8(fa, fb);
        *(bf16x8*)(smem + r * 640 + ((c * 16) ^ ((r & 7) << 4))) = v;
    }
    __syncthreads();

    // GEMM1: [64][320] @ [320][512]; wave w covers cols w*128..w*128+127
    f32x4 acc[4][8];
    #pragma unroll
    for (int m = 0; m < 4; ++m)
        #pragma unroll
        for (int n = 0; n < 8; ++n) acc[m][n] = (f32x4){0.f, 0.f, 0.f, 0.f};
    #pragma unroll 2
    for (int ks = 0; ks < 10; ++ks) {
        bf16x8 a[4];
        #pragma unroll
        for (int m = 0; m < 4; ++m) a[m] = lds_afrag(smem, 320, m * 16, ks * 32, lane);
        #pragma unroll
        for (int n = 0; n < 8; ++n) {
            bf16x8 b = glb_bfrag(W1T, 320, w * 128 + n * 16, ks * 32, lane);
            #pragma unroll
            for (int m = 0; m < 4; ++m) acc[m][n] = MFMA16(a[m], b, acc[m][n]);
        }
    }
    const int cb = w * 128;

    if (PASS == 0) {
        #pragma unroll
        for (int n = 0; n < 8; ++n) {
            int col = cb + n * 16 + (lane & 15);
            float bb = b1[col];
            float s = 0.f, q = 0.f;
            #pragma unroll
            for (int m = 0; m < 4; ++m)
                #pragma unroll
                for (int rr = 0; rr < 4; ++rr) {
                    int row = m * 16 + ((lane >> 4) << 2) + rr;
                    if (e0 + row < E) {
                        float h = acc[m][n][rr] + bb;
                        s += h; q += h * h;
                    }
                }
            s += __shfl_xor(s, 16); s += __shfl_xor(s, 32);
            q += __shfl_xor(q, 16); q += __shfl_xor(q, 32);
            if (lane < 16) { atomicAdd(&sum1[col], s); atomicAdd(&sq1[col], q); }
        }
        return;
    }

    // a1 = relu(bn1(h1)) -> smem [64][512] bf16 (reuse, barrier-guarded)
    __syncthreads();
    #pragma unroll
    for (int n = 0; n < 8; ++n) {
        int col = cb + n * 16 + (lane & 15);
        float bb = b1[col], sc = scale1[col], sh = shift1[col];
        #pragma unroll
        for (int m = 0; m < 4; ++m)
            #pragma unroll
            for (int rr = 0; rr < 4; ++rr) {
                int row = m * 16 + ((lane >> 4) << 2) + rr;
                float a = fmaxf(fmaf(acc[m][n][rr] + bb, sc, sh), 0.f);
                int off = (col * 2) ^ ((row & 7) << 4);
                *(bf16*)(smem + row * 1024 + off) = (bf16)a;
            }
    }
    __syncthreads();

    // GEMM2: [64][512] @ [512][256]; wave cols w*64..
    f32x4 acc2[4][4];
    #pragma unroll
    for (int m = 0; m < 4; ++m)
        #pragma unroll
        for (int n = 0; n < 4; ++n) acc2[m][n] = (f32x4){0.f, 0.f, 0.f, 0.f};
    #pragma unroll 2
    for (int ks = 0; ks < 16; ++ks) {
        bf16x8 a[4];
        #pragma unroll
        for (int m = 0; m < 4; ++m) a[m] = lds_afrag(smem, 512, m * 16, ks * 32, lane);
        #pragma unroll
        for (int n = 0; n < 4; ++n) {
            bf16x8 b = glb_bfrag(W2T, 512, w * 64 + n * 16, ks * 32, lane);
            #pragma unroll
            for (int m = 0; m < 4; ++m) acc2[m][n] = MFMA16(a[m], b, acc2[m][n]);
        }
    }
    const int cb2 = w * 64;

    if (PASS == 1) {
        #pragma unroll
        for (int n = 0; n < 4; ++n) {
            int col = cb2 + n * 16 + (lane & 15);
            float bb = b2[col];
            float s = 0.f, q = 0.f;
            #pragma unroll
            for (int m = 0; m < 4; ++m)
                #pragma unroll
                for (int rr = 0; rr < 4; ++rr) {
                    int row = m * 16 + ((lane >> 4) << 2) + rr;
                    if (e0 + row < E) {
                        float h = acc2[m][n][rr] + bb;
                        s += h; q += h * h;
                    }
                }
            s += __shfl_xor(s, 16); s += __shfl_xor(s, 32);
            q += __shfl_xor(q, 16); q += __shfl_xor(q, 32);
            if (lane < 16) { atomicAdd(&sum2[col], s); atomicAdd(&sq2[col], q); }
        }
        return;
    }

    // ---- PASS 2: full chain ----
    __syncthreads();  // done reading a1
    if (tid < 32) *(float*)(smem + 49152 + tid * 4) = W6[tid];  // stage W6 (region dead)
    // a2 = relu(bn2(h2)) -> smem [64][256]
    #pragma unroll
    for (int n = 0; n < 4; ++n) {
        int col = cb2 + n * 16 + (lane & 15);
        float bb = b2[col], sc = scale2[col], sh = shift2[col];
        #pragma unroll
        for (int m = 0; m < 4; ++m)
            #pragma unroll
            for (int rr = 0; rr < 4; ++rr) {
                int row = m * 16 + ((lane >> 4) << 2) + rr;
                float a = fmaxf(fmaf(acc2[m][n][rr] + bb, sc, sh), 0.f);
                int off = (col * 2) ^ ((row & 7) << 4);
                *(bf16*)(smem + row * 512 + off) = (bf16)a;
            }
    }
    __syncthreads();

    // GEMM3: [64][256] @ [256][128] -> relu -> a3 [64][128]
    f32x4 acc3[4][2];
    #pragma unroll
    for (int m = 0; m < 4; ++m)
        #pragma unroll
        for (int n = 0; n < 2; ++n) acc3[m][n] = (f32x4){0.f, 0.f, 0.f, 0.f};
    for (int ks = 0; ks < 8; ++ks) {
        bf16x8 a[4];
        #pragma unroll
        for (int m = 0; m < 4; ++m) a[m] = lds_afrag(smem, 256, m * 16, ks * 32, lane);
        #pragma unroll
        for (int n = 0; n < 2; ++n) {
            bf16x8 b = glb_bfrag(W3T, 256, w * 32 + n * 16, ks * 32, lane);
            #pragma unroll
            for (int m = 0; m < 4; ++m) acc3[m][n] = MFMA16(a[m], b, acc3[m][n]);
        }
    }
    __syncthreads();
    #pragma unroll
    for (int n = 0; n < 2; ++n) {
        int col = w * 32 + n * 16 + (lane & 15);
        float bb = b3[col];
        #pragma unroll
        for (int m = 0; m < 4; ++m)
            #pragma unroll
            for (int rr = 0; rr < 4; ++rr) {
                int row = m * 16 + ((lane >> 4) << 2) + rr;
                float a = fmaxf(acc3[m][n][rr] + bb, 0.f);
                int off = (col * 2) ^ ((row & 7) << 4);
                *(bf16*)(smem + row * 256 + off) = (bf16)a;
            }
    }
    __syncthreads();

    // GEMM4: [64][128] @ [128][64] -> relu -> a4 [64][64]
    f32x4 acc4[4];
    #pragma unroll
    for (int m = 0; m < 4; ++m) acc4[m] = (f32x4){0.f, 0.f, 0.f, 0.f};
    for (int ks = 0; ks < 4; ++ks) {
        bf16x8 a[4];
        #pragma unroll
        for (int m = 0; m < 4; ++m) a[m] = lds_afrag(smem, 128, m * 16, ks * 32, lane);
        bf16x8 b = glb_bfrag(W4T, 128, w * 16, ks * 32, lane);
        #pragma unroll
        for (int m = 0; m < 4; ++m) acc4[m] = MFMA16(a[m], b, acc4[m]);
    }
    __syncthreads();
    {
        int col = w * 16 + (lane & 15);
        float bb = b4[col];
        #pragma unroll
        for (int m = 0; m < 4; ++m)
            #pragma unroll
            for (int rr = 0; rr < 4; ++rr) {
                int row = m * 16 + ((lane >> 4) << 2) + rr;
                float a = fmaxf(acc4[m][rr] + bb, 0.f);
                int off = (col * 2) ^ ((row & 7) << 4);
                *(bf16*)(smem + row * 128 + off) = (bf16)a;
            }
    }
    __syncthreads();

    // GEMM5: [64][64] @ [64][32] -> relu -> a5 f32 at smem+16384 (waves 0,1)
    if (w < 2) {
        f32x4 acc5[4];
        #pragma unroll
        for (int m = 0; m < 4; ++m) acc5[m] = (f32x4){0.f, 0.f, 0.f, 0.f};
        for (int ks = 0; ks < 2; ++ks) {
            bf16x8 a[4];
            #pragma unroll
            for (int m = 0; m < 4; ++m) a[m] = lds_afrag(smem, 64, m * 16, ks * 32, lane);
            bf16x8 b = glb_bfrag(W5T, 64, w * 16, ks * 32, lane);
            #pragma unroll
            for (int m = 0; m < 4; ++m) acc5[m] = MFMA16(a[m], b, acc5[m]);
        }
        int col = w * 16 + (lane & 15);
        float bb = b5[col];
        float* a5f = (float*)(smem + 16384);
        #pragma unroll
        for (int m = 0; m < 4; ++m)
            #pragma unroll
            for (int rr = 0; rr < 4; ++rr) {
                int row = m * 16 + ((lane >> 4) << 2) + rr;
                a5f[row * 32 + col] = fmaxf(acc5[m][rr] + bb, 0.f);
            }
    }
    __syncthreads();

    // final: out = a5 @ W6 + b6
    if (tid < 64) {
        int ge = e0 + tid;
        if (ge < E) {
            const float* a5f = (const float*)(smem + 16384) + tid * 32;
            const float* w6 = (const float*)(smem + 49152);
            float s = b6[0];
            #pragma unroll
            for (int k = 0; k < 32; ++k) {
                int kk = (k + tid) & 31;
                s = fmaf(a5f[kk], w6[kk], s);
            }
            out[ge] = s;
        }
    }
}

// ---------------- launch ----------------

extern "C" void kernel_launch(void* const* d_in, const int* in_sizes, int n_in,
                              void* d_out, int out_size, void* d_ws, size_t ws_size,
                              hipStream_t stream) {
    const float* x      = (const float*)d_in[0];
    const int*   ei     = (const int*)d_in[1];
    const float* ef     = (const float*)d_in[2];
    const float* W_nb   = (const float*)d_in[4];
    const float* b_nb   = (const float*)d_in[5];
    const float* W_self = (const float*)d_in[6];
    const float* b_self = (const float*)d_in[7];
    const float* W1 = (const float*)d_in[8];  const float* b1 = (const float*)d_in[9];
    const float* W2 = (const float*)d_in[10]; const float* b2 = (const float*)d_in[11];
    const float* W3 = (const float*)d_in[12]; const float* b3 = (const float*)d_in[13];
    const float* W4 = (const float*)d_in[14]; const float* b4 = (const float*)d_in[15];
    const float* W5 = (const float*)d_in[16]; const float* b5 = (const float*)d_in[17];
    const float* W6 = (const float*)d_in[18]; const float* b6 = (const float*)d_in[19];
    const float* g1 = (const float*)d_in[20]; const float* beta1 = (const float*)d_in[21];
    const float* g2 = (const float*)d_in[22]; const float* beta2 = (const float*)d_in[23];

    const int N = in_sizes[0] / 128;
    const int E = in_sizes[1] / 2;

    char* ws = (char*)d_ws;
    size_t off = 0;
    auto alloc = [&](size_t bytes) {
        size_t o = off;
        off = (off + bytes + 255) & ~(size_t)255;
        return o;
    };
    size_t oDeg = alloc((size_t)N * 4);
    size_t oCur = alloc((size_t)N * 4);
    size_t oSum1 = alloc(512 * 4), oSq1 = alloc(512 * 4);
    size_t oSum2 = alloc(256 * 4), oSq2 = alloc(256 * 4);
    size_t zeroEnd = off;
    size_t oOff = alloc((size_t)(N + 1) * 4);
    size_t oInv = alloc((size_t)N * 4);
    size_t oEid = alloc((size_t)E * 4);
    size_t oSm  = alloc((size_t)N * 192 * 4);
    size_t oXb1 = alloc((size_t)N * 128 * 4);
    size_t oXb2 = alloc((size_t)N * 128 * 4);
    size_t oScale1 = alloc(512 * 4), oShift1 = alloc(512 * 4);
    size_t oScale2 = alloc(256 * 4), oShift2 = alloc(256 * 4);
    size_t oWcat = alloc(128 * 320 * 2);
    size_t oW1T = alloc((size_t)512 * 320 * 2);
    size_t oW2T = alloc((size_t)256 * 512 * 2);
    size_t oW3T = alloc((size_t)128 * 256 * 2);
    size_t oW4T = alloc((size_t)64 * 128 * 2);
    size_t oW5T = alloc((size_t)32 * 64 * 2);
    if (ws_size < off) return;  // workspace too small: fail loudly (absmax check will trip)

    float* deg = (float*)(ws + oDeg);
    unsigned* cursor = (unsigned*)(ws + oCur);
    float* sum1 = (float*)(ws + oSum1); float* sq1 = (float*)(ws + oSq1);
    float* sum2 = (float*)(ws + oSum2); float* sq2 = (float*)(ws + oSq2);
    unsigned* offsets = (unsigned*)(ws + oOff);
    float* invdeg = (float*)(ws + oInv);
    unsigned* eid = (unsigned*)(ws + oEid);
    float* sm  = (float*)(ws + oSm);
    float* xb1 = (float*)(ws + oXb1);
    float* xb2 = (float*)(ws + oXb2);
    float* scale1 = (float*)(ws + oScale1); float* shift1 = (float*)(ws + oShift1);
    float* scale2 = (float*)(ws + oScale2); float* shift2 = (float*)(ws + oShift2);
    bf16* WcatT = (bf16*)(ws + oWcat);
    bf16* W1T = (bf16*)(ws + oW1T);
    bf16* W2T = (bf16*)(ws + oW2T);
    bf16* W3T = (bf16*)(ws + oW3T);
    bf16* W4T = (bf16*)(ws + oW4T);
    bf16* W5T = (bf16*)(ws + oW5T);

    hipMemsetAsync(ws, 0, zeroEnd, stream);

    // weight transposes -> bf16 [N][K]
    k_transpose<<<(128 * 128 + 255) / 256, 256, 0, stream>>>(W_self, WcatT, 128, 128, 320, 0);
    k_transpose<<<(192 * 128 + 255) / 256, 256, 0, stream>>>(W_nb, WcatT, 192, 128, 320, 128);
    k_transpose<<<(320 * 512 + 255) / 256, 256, 0, stream>>>(W1, W1T, 320, 512, 320, 0);
    k_transpose<<<(512 * 256 + 255) / 256, 256, 0, stream>>>(W2, W2T, 512, 256, 512, 0);
    k_transpose<<<(256 * 128 + 255) / 256, 256, 0, stream>>>(W3, W3T, 256, 128, 256, 0);
    k_transpose<<<(128 * 64 + 255) / 256, 256, 0, stream>>>(W4, W4T, 128, 64, 128, 0);
    k_transpose<<<(64 * 32 + 255) / 256, 256, 0, stream>>>(W5, W5T, 64, 32, 64, 0);

    const int* dst = ei + E;
    k_deg<<<(E + 255) / 256, 256, 0, stream>>>(dst, deg, E);
    k_scan<<<1, 1024, 0, stream>>>(deg, offsets, invdeg, N);
    k_scatter<<<(E + 255) / 256, 256, 0, stream>>>(dst, offsets, cursor, eid, E);

    // conv layer 1
    k_agg<<<(N + 15) / 16, 256, 0, stream>>>(x, ef, ei, offsets, invdeg, eid, sm, N);
    k_nodegemm<<<(N + 63) / 64, 256, 0, stream>>>(x, sm, WcatT, b_self, b_nb, offsets, xb1, N);
    // conv layer 2
    k_agg<<<(N + 15) / 16, 256, 0, stream>>>(xb1, ef, ei, offsets, invdeg, eid, sm, N);
    k_nodegemm<<<(N + 63) / 64, 256, 0, stream>>>(xb1, sm, WcatT, b_self, b_nb, offsets, xb2, N);

    const float invE = 1.0f / (float)E;
    const int mlpGrid = (E + 63) / 64;
    k_mlp<0><<<mlpGrid, 256, 0, stream>>>(xb2, ei, ef, W1T, b1, W2T, b2, W3T, b3, W4T, b4,
                                          W5T, b5, W6, b6, scale1, shift1, scale2, shift2,
                                          sum1, sq1, sum2, sq2, (float*)d_out, E);
    k_finalize<<<2, 256, 0, stream>>>(sum1, sq1, g1, beta1, scale1, shift1, 512, invE);
    k_mlp<1><<<mlpGrid, 256, 0, stream>>>(xb2, ei, ef, W1T, b1, W2T, b2, W3T, b3, W4T, b4,
                                          W5T, b5, W6, b6, scale1, shift1, scale2, shift2,
                                          sum1, sq1, sum2, sq2, (float*)d_out, E);
    k_finalize<<<1, 256, 0, stream>>>(sum2, sq2, g2, beta2, scale2, shift2, 256, invE);
    k_mlp<2><<<mlpGrid, 256, 0, stream>>>(xb2, ei, ef, W1T, b1, W2T, b2, W3T, b3, W4T, b4,
                                          W5T, b5, W6, b6, scale1, shift1, scale2, shift2,
                                          sum1, sq1, sum2, sq2, (float*)d_out, E);
}